// Round 2
// baseline (1017.020 us; speedup 1.0000x reference)
//
#include <hip/hip_runtime.h>
#include <cstdint>
#include <cstddef>

typedef _Float16 f16;
typedef _Float16 half4 __attribute__((ext_vector_type(4)));
typedef _Float16 half8 __attribute__((ext_vector_type(8)));
typedef float f32x4 __attribute__((ext_vector_type(4)));

#define BN_EPS 1e-5f

// ---------------- workspace layout (bytes) ----------------
static constexpr size_t OFF_XB  = 0;          // f16 [64][32][32][256] NHWC      33,554,432
static constexpr size_t OFF_ZB  = 33554432;   // f16 [64][16][16][256] NHWC       8,388,608
static constexpr size_t OFF_WX  = 41943040;   // f16 [9][256][256]                1,179,648
static constexpr size_t OFF_WZ  = 43122688;   // f16 [9][256][256]                1,179,648
static constexpr size_t OFF_BNX = 44302336;   // f32 scale[256], bias[256]            2,048
static constexpr size_t OFF_BNZ = 44304384;   //                                      2,048
static constexpr size_t OFF_XFH = 44306432;   // f16 [16384][30][32]             31,457,280
static constexpr size_t OFF_ZFH = 75763712;   // f16 [16384][14][16]              7,340,032

// ---------------- NCHW fp32 -> NHWC f16 transpose ----------------
template <int H, int W>
__global__ __launch_bounds__(256) void nchw_to_nhwc_f16(
    const float* __restrict__ src, f16* __restrict__ dst) {
  __shared__ float tile[64][W + 1];
  const int bid = blockIdx.x;
  const int c0 = (bid & 3) << 6;
  const int h = (bid >> 2) % H;
  const int b = bid / (4 * H);
  const float* sp = src + ((b * 256 + c0) * H + h) * W;
  for (int i = threadIdx.x; i < 64 * W; i += 256) {
    int cl = i / W, w = i - cl * W;
    tile[cl][w] = sp[cl * (H * W) + w];
  }
  __syncthreads();
  f16* dp = dst + (b * H + h) * W * 256 + c0;
  for (int i = threadIdx.x; i < 64 * W; i += 256) {
    int w = i >> 6, cl = i & 63;
    dp[w * 256 + cl] = (f16)tile[cl][w];
  }
}

// ---------------- weight repack: OIHW fp32 -> [khw][cout][cin] f16 ----------------
__global__ __launch_bounds__(256) void prep_w(const float* __restrict__ w,
                                              f16* __restrict__ wA) {
  int idx = blockIdx.x * 256 + threadIdx.x;
  int cin = idx & 255;
  int cout = (idx >> 8) & 255;
  int khw = idx >> 16;
  wA[idx] = (f16)w[(cout * 256 + cin) * 9 + khw];
}

// ---------------- BN fold ----------------
__global__ void prep_bn(const float* __restrict__ gamma, const float* __restrict__ beta,
                        const float* __restrict__ mean, const float* __restrict__ var,
                        float* __restrict__ bnout) {
  int c = threadIdx.x;
  float inv = gamma[c] / sqrtf(var[c] + BN_EPS);
  bnout[c] = inv;
  bnout[256 + c] = beta[c] - mean[c] * inv;
}

// ---------------- fused implicit-im2col conv3x3 + BN (MFMA f16) ----------------
__device__ __forceinline__ void gl_lds16(const f16* g, f16* l) {
  __builtin_amdgcn_global_load_lds((__attribute__((address_space(1))) void*)g,
                                   (__attribute__((address_space(3))) void*)l, 16, 0, 0);
}

template <int HIN, int WIN, int HOUT, int WOUT, int WPAD>
__global__ __launch_bounds__(256) void conv_gemm(
    const f16* __restrict__ inp,   // NHWC f16 [B][HIN][WIN][256]
    const f16* __restrict__ wA,    // [9][256][256]
    const float* __restrict__ bn,  // scale[256], bias[256]
    f16* __restrict__ out) {       // f16 [b*256+cout][HOUT][WPAD]
  constexpr int NPIX = HOUT * WOUT;
  __shared__ f16 As[128 * 32];
  __shared__ f16 Bs[128 * 32];
  const int tid = threadIdx.x;
  const int wid = tid >> 6, lane = tid & 63;
  const int nblk = blockIdx.x, mblk = blockIdx.y;
  const int wm = (wid >> 1) << 6, wn = (wid & 1) << 6;
  const int q = lane >> 4, lm = lane & 15;
  const int sr = lane >> 2, sc = lane & 3;

  const int row0 = (wid << 5) + sr;
  const int row1 = row0 + 16;
  const int swz0 = (sc ^ (row0 & 3)) << 3;
  const int swz1 = (sc ^ (row1 & 3)) << 3;

  int ib0, ib1;
  {
    int n0 = nblk * 128 + row0;
    int b = n0 / NPIX, r = n0 - b * NPIX;
    int oh = r / WOUT, ow = r - oh * WOUT;
    ib0 = ((b * HIN + oh) * WIN + ow) << 8;
    int n1 = n0 + 16;
    b = n1 / NPIX; r = n1 - b * NPIX;
    oh = r / WOUT; ow = r - oh * WOUT;
    ib1 = ((b * HIN + oh) * WIN + ow) << 8;
  }
  const int acol0 = ((mblk << 7) + row0) << 8;
  const int acol1 = ((mblk << 7) + row1) << 8;

  f16* lds_a0 = &As[(wid << 5) * 32];
  f16* lds_a1 = &As[((wid << 5) + 16) * 32];
  f16* lds_b0 = &Bs[(wid << 5) * 32];
  f16* lds_b1 = &Bs[((wid << 5) + 16) * 32];

  f32x4 acc[4][4] = {};
  const int swf = (q ^ (lm & 3)) << 3;

  for (int kt = 0; kt < 72; ++kt) {
    const int khw = kt >> 3;
    const int cin0 = (kt & 7) << 5;
    const int kh = khw / 3, kw = khw - kh * 3;
    const int wbase = khw * 65536 + cin0;
    gl_lds16(wA + wbase + acol0 + swz0, lds_a0);
    gl_lds16(wA + wbase + acol1 + swz1, lds_a1);
    const int ioff = ((kh * WIN + kw) << 8) + cin0;
    gl_lds16(inp + ib0 + ioff + swz0, lds_b0);
    gl_lds16(inp + ib1 + ioff + swz1, lds_b1);
    __syncthreads();

    half8 af[4], bf[4];
#pragma unroll
    for (int f = 0; f < 4; ++f) {
      af[f] = *(const half8*)&As[((wm + (f << 4) + lm) << 5) + swf];
      bf[f] = *(const half8*)&Bs[((wn + (f << 4) + lm) << 5) + swf];
    }
#pragma unroll
    for (int fm = 0; fm < 4; ++fm)
#pragma unroll
      for (int fn = 0; fn < 4; ++fn)
        acc[fm][fn] =
            __builtin_amdgcn_mfma_f32_16x16x32_f16(af[fm], bf[fn], acc[fm][fn], 0, 0, 0);
    __syncthreads();
  }

  // epilogue: BN + f16 padded store. C/D: row m = q*4+reg, col n = lm.
#pragma unroll
  for (int fn = 0; fn < 4; ++fn) {
    int n_g = (nblk << 7) + wn + (fn << 4) + lm;
    int b = n_g / NPIX, r = n_g - b * NPIX;
    int oh = r / WOUT, ow = r - oh * WOUT;
    f16* op = out + ((b * 256) * HOUT + oh) * WPAD + ow;
#pragma unroll
    for (int fm = 0; fm < 4; ++fm) {
      int m0 = (mblk << 7) + wm + (fm << 4) + (q << 2);
#pragma unroll
      for (int rg = 0; rg < 4; ++rg) {
        int m = m0 + rg;
        op[m * (HOUT * WPAD)] = (f16)(acc[fm][fn][rg] * bn[m] + bn[256 + m]);
      }
    }
  }
}

// ---------------- depthwise xcorr v2 ----------------
// Block = 256 threads, 5 channels. Per channel: 45 threads = 9 oy-pairs x 5 ox-quads.
// Thread computes 2x4 outputs; z row slides in registers (read once per u).
static constexpr int XS_STRIDE = 40;    // halves per x row (80 B, b128-aligned, bank-spread)
static constexpr int XS_CH = 31 * 40;   // 31 rows: +1 clamp-pad row
static constexpr int ZS_CH = 224;       // 14 x 16 halves

__global__ __launch_bounds__(256) void xcorr_dw2(const f16* __restrict__ zfh,
                                                 const f16* __restrict__ xfh,
                                                 float* __restrict__ out) {
  __shared__ f16 xs[5 * XS_CH];  // 12,400 B
  __shared__ f16 zs[5 * ZS_CH];  //  2,240 B
  const int t = threadIdx.x;
  const int ch0 = blockIdx.x * 5;

  // ---- stage x: 5 ch x 30 rows x 4 half8 chunks = 600 ----
  for (int i = t; i < 600; i += 256) {
    int ch = i / 120, rem = i - ch * 120;
    int row = rem >> 2, col = (rem & 3) << 3;
    if (ch0 + ch < 16384) {
      half8 v = *(const half8*)(xfh + (ch0 + ch) * 960 + row * 32 + col);
      *(half8*)(xs + ch * XS_CH + row * XS_STRIDE + col) = v;
    }
  }
  // ---- stage z: 5 ch x 28 half8 chunks = 140 ----
  for (int i = t; i < 140; i += 256) {
    int ch = i / 28, rem = i - ch * 28;
    if (ch0 + ch < 16384) {
      half8 v = *(const half8*)(zfh + (ch0 + ch) * 224 + rem * 8);
      *(half8*)(zs + ch * ZS_CH + rem * 8) = v;
    }
  }
  __syncthreads();

  int lc = t / 45;
  int r = t - lc * 45;
  const bool ok = (lc < 5) && (ch0 + lc < 16384);
  if (lc > 4) { lc = 4; }           // idle threads compute ch 4 (masked at store)
  const int oyq = r / 5, oxq = r - oyq * 5;
  const int oy0 = oyq * 2;
  const f16* xb = xs + lc * XS_CH;
  const f16* zb = zs + lc * ZS_CH;

  float acc0[4] = {0.f, 0.f, 0.f, 0.f};
  float acc1[4] = {0.f, 0.f, 0.f, 0.f};
  float zc[14], zp[14];

#pragma unroll
  for (int i = 0; i < 15; ++i) {
    int yy = oy0 + i;
    if (yy > 29) yy = 29;  // clamp (oyq==8 tail; results masked)
    // x row: cols oxq*4 .. +19 via 5 x b64
    float xr[20];
#pragma unroll
    for (int k = 0; k < 5; ++k) {
      half4 h = *(const half4*)(xb + yy * XS_STRIDE + oxq * 4 + k * 4);
#pragma unroll
      for (int e = 0; e < 4; ++e) xr[k * 4 + e] = (float)h[e];
    }
    if (i <= 13) {
      half8 z0 = *(const half8*)(zb + i * 16);
      half8 z1 = *(const half8*)(zb + i * 16 + 8);
#pragma unroll
      for (int e = 0; e < 8; ++e) zc[e] = (float)z0[e];
#pragma unroll
      for (int e = 0; e < 6; ++e) zc[8 + e] = (float)z1[e];
#pragma unroll
      for (int v = 0; v < 14; ++v)
#pragma unroll
        for (int j = 0; j < 4; ++j) acc0[j] = fmaf(zc[v], xr[v + j], acc0[j]);
    }
    if (i >= 1) {
#pragma unroll
      for (int v = 0; v < 14; ++v)
#pragma unroll
        for (int j = 0; j < 4; ++j) acc1[j] = fmaf(zp[v], xr[v + j], acc1[j]);
    }
    if (i <= 13) {
#pragma unroll
      for (int v = 0; v < 14; ++v) zp[v] = zc[v];
    }
  }

  if (ok) {
    float* op = out + (ch0 + lc) * 289;
#pragma unroll
    for (int j = 0; j < 4; ++j) {
      int ox = oxq * 4 + j;
      if (ox < 17) {
        op[oy0 * 17 + ox] = acc0[j];
        if (oyq < 8) op[(oy0 + 1) * 17 + ox] = acc1[j];
      }
    }
  }
}

extern "C" void kernel_launch(void* const* d_in, const int* in_sizes, int n_in,
                              void* d_out, int out_size, void* d_ws, size_t ws_size,
                              hipStream_t stream) {
  const float* z = (const float*)d_in[0];
  const float* x = (const float*)d_in[1];
  const float* w_z = (const float*)d_in[2];
  const float* w_x = (const float*)d_in[3];
  const float* gamma_z = (const float*)d_in[4];
  const float* beta_z = (const float*)d_in[5];
  const float* mean_z = (const float*)d_in[6];
  const float* var_z = (const float*)d_in[7];
  const float* gamma_x = (const float*)d_in[8];
  const float* beta_x = (const float*)d_in[9];
  const float* mean_x = (const float*)d_in[10];
  const float* var_x = (const float*)d_in[11];

  char* ws = (char*)d_ws;
  f16* xb = (f16*)(ws + OFF_XB);
  f16* zb = (f16*)(ws + OFF_ZB);
  f16* wxA = (f16*)(ws + OFF_WX);
  f16* wzA = (f16*)(ws + OFF_WZ);
  float* bnx = (float*)(ws + OFF_BNX);
  float* bnz = (float*)(ws + OFF_BNZ);
  f16* xfh = (f16*)(ws + OFF_XFH);
  f16* zfh = (f16*)(ws + OFF_ZFH);
  float* out = (float*)d_out;

  nchw_to_nhwc_f16<32, 32><<<64 * 32 * 4, 256, 0, stream>>>(x, xb);
  nchw_to_nhwc_f16<16, 16><<<64 * 16 * 4, 256, 0, stream>>>(z, zb);
  prep_w<<<2304, 256, 0, stream>>>(w_x, wxA);
  prep_w<<<2304, 256, 0, stream>>>(w_z, wzA);
  prep_bn<<<1, 256, 0, stream>>>(gamma_x, beta_x, mean_x, var_x, bnx);
  prep_bn<<<1, 256, 0, stream>>>(gamma_z, beta_z, mean_z, var_z, bnz);

  conv_gemm<32, 32, 30, 30, 32><<<dim3(450, 2), 256, 0, stream>>>(xb, wxA, bnx, xfh);
  conv_gemm<16, 16, 14, 14, 16><<<dim3(98, 2), 256, 0, stream>>>(zb, wzA, bnz, zfh);

  xcorr_dw2<<<3277, 256, 0, stream>>>(zfh, xfh, out);
}

// Round 3
// 357.797 us; speedup vs baseline: 2.8425x; 2.8425x over previous
//
#include <hip/hip_runtime.h>
#include <cstdint>
#include <cstddef>

typedef _Float16 f16;
typedef _Float16 half4 __attribute__((ext_vector_type(4)));
typedef _Float16 half8 __attribute__((ext_vector_type(8)));
typedef float f32x4 __attribute__((ext_vector_type(4)));

#define BN_EPS 1e-5f

// ---------------- workspace layout (bytes) ----------------
static constexpr size_t OFF_XB  = 0;          // f16 [64][32][32][256] NHWC      33,554,432
static constexpr size_t OFF_ZB  = 33554432;   // f16 [64][16][16][256] NHWC       8,388,608
static constexpr size_t OFF_WX  = 41943040;   // f16 [9][256][256]                1,179,648
static constexpr size_t OFF_WZ  = 43122688;   // f16 [9][256][256]                1,179,648
static constexpr size_t OFF_BNX = 44302336;   // f32 scale[256], bias[256]            2,048
static constexpr size_t OFF_BNZ = 44304384;   //                                      2,048
static constexpr size_t OFF_XFH = 44306432;   // f16 [16384][30][32]             31,457,280
static constexpr size_t OFF_ZFH = 75763712;   // f16 [16384][14][16]              7,340,032

// ---------------- NCHW fp32 -> NHWC f16 transpose ----------------
template <int H, int W>
__global__ __launch_bounds__(256) void nchw_to_nhwc_f16(
    const float* __restrict__ src, f16* __restrict__ dst) {
  __shared__ float tile[64][W + 1];
  const int bid = blockIdx.x;
  const int c0 = (bid & 3) << 6;
  const int h = (bid >> 2) % H;
  const int b = bid / (4 * H);
  const float* sp = src + ((b * 256 + c0) * H + h) * W;
  for (int i = threadIdx.x; i < 64 * W; i += 256) {
    int cl = i / W, w = i - cl * W;
    tile[cl][w] = sp[cl * (H * W) + w];
  }
  __syncthreads();
  f16* dp = dst + (b * H + h) * W * 256 + c0;
  for (int i = threadIdx.x; i < 64 * W; i += 256) {
    int w = i >> 6, cl = i & 63;
    dp[w * 256 + cl] = (f16)tile[cl][w];
  }
}

// ---------------- weight repack: OIHW fp32 -> [khw][cout][cin] f16 ----------------
__global__ __launch_bounds__(256) void prep_w(const float* __restrict__ w,
                                              f16* __restrict__ wA) {
  int idx = blockIdx.x * 256 + threadIdx.x;
  int cin = idx & 255;
  int cout = (idx >> 8) & 255;
  int khw = idx >> 16;
  wA[idx] = (f16)w[(cout * 256 + cin) * 9 + khw];
}

// ---------------- BN fold ----------------
__global__ void prep_bn(const float* __restrict__ gamma, const float* __restrict__ beta,
                        const float* __restrict__ mean, const float* __restrict__ var,
                        float* __restrict__ bnout) {
  int c = threadIdx.x;
  float inv = gamma[c] / sqrtf(var[c] + BN_EPS);
  bnout[c] = inv;
  bnout[256 + c] = beta[c] - mean[c] * inv;
}

// ---------------- fused implicit-im2col conv3x3 + BN (MFMA f16) ----------------
__device__ __forceinline__ void gl_lds16(const f16* g, f16* l) {
  __builtin_amdgcn_global_load_lds((__attribute__((address_space(1))) void*)g,
                                   (__attribute__((address_space(3))) void*)l, 16, 0, 0);
}

template <int HIN, int WIN, int HOUT, int WOUT, int WPAD>
__global__ __launch_bounds__(256) void conv_gemm(
    const f16* __restrict__ inp,   // NHWC f16 [B][HIN][WIN][256]
    const f16* __restrict__ wA,    // [9][256][256]
    const float* __restrict__ bn,  // scale[256], bias[256]
    f16* __restrict__ out) {       // f16 [b*256+cout][HOUT][WPAD]
  constexpr int NPIX = HOUT * WOUT;
  __shared__ f16 As[128 * 32];
  __shared__ f16 Bs[128 * 32];
  const int tid = threadIdx.x;
  const int wid = tid >> 6, lane = tid & 63;
  const int nblk = blockIdx.x, mblk = blockIdx.y;
  const int wm = (wid >> 1) << 6, wn = (wid & 1) << 6;
  const int q = lane >> 4, lm = lane & 15;
  const int sr = lane >> 2, sc = lane & 3;

  const int row0 = (wid << 5) + sr;
  const int row1 = row0 + 16;
  const int swz0 = (sc ^ (row0 & 3)) << 3;
  const int swz1 = (sc ^ (row1 & 3)) << 3;

  int ib0, ib1;
  {
    int n0 = nblk * 128 + row0;
    int b = n0 / NPIX, r = n0 - b * NPIX;
    int oh = r / WOUT, ow = r - oh * WOUT;
    ib0 = ((b * HIN + oh) * WIN + ow) << 8;
    int n1 = n0 + 16;
    b = n1 / NPIX; r = n1 - b * NPIX;
    oh = r / WOUT; ow = r - oh * WOUT;
    ib1 = ((b * HIN + oh) * WIN + ow) << 8;
  }
  const int acol0 = ((mblk << 7) + row0) << 8;
  const int acol1 = ((mblk << 7) + row1) << 8;

  f16* lds_a0 = &As[(wid << 5) * 32];
  f16* lds_a1 = &As[((wid << 5) + 16) * 32];
  f16* lds_b0 = &Bs[(wid << 5) * 32];
  f16* lds_b1 = &Bs[((wid << 5) + 16) * 32];

  f32x4 acc[4][4] = {};
  const int swf = (q ^ (lm & 3)) << 3;

  for (int kt = 0; kt < 72; ++kt) {
    const int khw = kt >> 3;
    const int cin0 = (kt & 7) << 5;
    const int kh = khw / 3, kw = khw - kh * 3;
    const int wbase = khw * 65536 + cin0;
    gl_lds16(wA + wbase + acol0 + swz0, lds_a0);
    gl_lds16(wA + wbase + acol1 + swz1, lds_a1);
    const int ioff = ((kh * WIN + kw) << 8) + cin0;
    gl_lds16(inp + ib0 + ioff + swz0, lds_b0);
    gl_lds16(inp + ib1 + ioff + swz1, lds_b1);
    __syncthreads();

    half8 af[4], bf[4];
#pragma unroll
    for (int f = 0; f < 4; ++f) {
      af[f] = *(const half8*)&As[((wm + (f << 4) + lm) << 5) + swf];
      bf[f] = *(const half8*)&Bs[((wn + (f << 4) + lm) << 5) + swf];
    }
#pragma unroll
    for (int fm = 0; fm < 4; ++fm)
#pragma unroll
      for (int fn = 0; fn < 4; ++fn)
        acc[fm][fn] =
            __builtin_amdgcn_mfma_f32_16x16x32_f16(af[fm], bf[fn], acc[fm][fn], 0, 0, 0);
    __syncthreads();
  }

  // epilogue: BN + f16 padded store. C/D: row m = q*4+reg, col n = lm.
#pragma unroll
  for (int fn = 0; fn < 4; ++fn) {
    int n_g = (nblk << 7) + wn + (fn << 4) + lm;
    int b = n_g / NPIX, r = n_g - b * NPIX;
    int oh = r / WOUT, ow = r - oh * WOUT;
    f16* op = out + ((b * 256) * HOUT + oh) * WPAD + ow;
#pragma unroll
    for (int fm = 0; fm < 4; ++fm) {
      int m0 = (mblk << 7) + wm + (fm << 4) + (q << 2);
#pragma unroll
      for (int rg = 0; rg < 4; ++rg) {
        int m = m0 + rg;
        op[m * (HOUT * WPAD)] = (f16)(acc[fm][fn][rg] * bn[m] + bn[256 + m]);
      }
    }
  }
}

// ---------------- depthwise xcorr v3 ----------------
// 3 channels / 256-thread block; 85 tasks per channel (17 oy x 5 ox-quads).
// Thread computes a 1x4 output strip; low register footprint, u-loop unroll 2.
static constexpr int XST = 40;          // halves per x row in LDS (80 B)
static constexpr int XCH = 30 * XST;    // 1200 halves per channel
static constexpr int ZCH = 14 * 16;     // 224 halves per channel

__global__ __launch_bounds__(256) void xcorr_dw3(const f16* __restrict__ zfh,
                                                 const f16* __restrict__ xfh,
                                                 float* __restrict__ out) {
  __shared__ f16 xs[3 * XCH];  // 7200 B
  __shared__ f16 zs[3 * ZCH];  // 1344 B
  const int t = threadIdx.x;
  const int ch0 = blockIdx.x * 3;

  // stage x: 3 ch x 30 rows x 4 half8 chunks = 360
  for (int i = t; i < 360; i += 256) {
    int ch = i / 120, rem = i - ch * 120;
    int row = rem >> 2, col = (rem & 3) << 3;
    if (ch0 + ch < 16384)
      *(half8*)(xs + ch * XCH + row * XST + col) =
          *(const half8*)(xfh + (size_t)(ch0 + ch) * 960 + row * 32 + col);
  }
  // stage z: 3 ch x 28 half8 chunks = 84
  for (int i = t; i < 84; i += 256) {
    int ch = i / 28, rem = i - ch * 28;
    if (ch0 + ch < 16384)
      *(half8*)(zs + ch * ZCH + rem * 8) =
          *(const half8*)(zfh + (size_t)(ch0 + ch) * 224 + rem * 8);
  }
  __syncthreads();

  int lc = t / 85;
  int r = t - lc * 85;
  const bool ok = (lc < 3) && (ch0 + lc < 16384);
  if (lc > 2) lc = 2;
  const int oy = r / 5, oxq = r - oy * 5, ox0 = oxq * 4;
  const f16* xb = xs + lc * XCH;
  const f16* zb = zs + lc * ZCH;

  float acc[4] = {0.f, 0.f, 0.f, 0.f};

#pragma unroll 2
  for (int u = 0; u < 14; ++u) {
    // x row: 20 halves from ox0 (only 0..16 used by valid outputs)
    float xr[20];
#pragma unroll
    for (int k = 0; k < 5; ++k) {
      half4 h = *(const half4*)(xb + (oy + u) * XST + ox0 + k * 4);
#pragma unroll
      for (int e = 0; e < 4; ++e) xr[k * 4 + e] = (float)h[e];
    }
    // z row: 14 taps (cols 14,15 of the padded row are ignored)
    float zc[14];
    {
      half8 z0 = *(const half8*)(zb + u * 16);
      half8 z1 = *(const half8*)(zb + u * 16 + 8);
#pragma unroll
      for (int e = 0; e < 8; ++e) zc[e] = (float)z0[e];
#pragma unroll
      for (int e = 0; e < 6; ++e) zc[8 + e] = (float)z1[e];
    }
#pragma unroll
    for (int v = 0; v < 14; ++v)
#pragma unroll
      for (int j = 0; j < 4; ++j) acc[j] = fmaf(zc[v], xr[v + j], acc[j]);
  }

  if (ok) {
    float* op = out + (size_t)(ch0 + lc) * 289 + oy * 17;
#pragma unroll
    for (int j = 0; j < 4; ++j) {
      int ox = ox0 + j;
      if (ox < 17) op[ox] = acc[j];
    }
  }
}

extern "C" void kernel_launch(void* const* d_in, const int* in_sizes, int n_in,
                              void* d_out, int out_size, void* d_ws, size_t ws_size,
                              hipStream_t stream) {
  const float* z = (const float*)d_in[0];
  const float* x = (const float*)d_in[1];
  const float* w_z = (const float*)d_in[2];
  const float* w_x = (const float*)d_in[3];
  const float* gamma_z = (const float*)d_in[4];
  const float* beta_z = (const float*)d_in[5];
  const float* mean_z = (const float*)d_in[6];
  const float* var_z = (const float*)d_in[7];
  const float* gamma_x = (const float*)d_in[8];
  const float* beta_x = (const float*)d_in[9];
  const float* mean_x = (const float*)d_in[10];
  const float* var_x = (const float*)d_in[11];

  char* ws = (char*)d_ws;
  f16* xb = (f16*)(ws + OFF_XB);
  f16* zb = (f16*)(ws + OFF_ZB);
  f16* wxA = (f16*)(ws + OFF_WX);
  f16* wzA = (f16*)(ws + OFF_WZ);
  float* bnx = (float*)(ws + OFF_BNX);
  float* bnz = (float*)(ws + OFF_BNZ);
  f16* xfh = (f16*)(ws + OFF_XFH);
  f16* zfh = (f16*)(ws + OFF_ZFH);
  float* out = (float*)d_out;

  nchw_to_nhwc_f16<32, 32><<<64 * 32 * 4, 256, 0, stream>>>(x, xb);
  nchw_to_nhwc_f16<16, 16><<<64 * 16 * 4, 256, 0, stream>>>(z, zb);
  prep_w<<<2304, 256, 0, stream>>>(w_x, wxA);
  prep_w<<<2304, 256, 0, stream>>>(w_z, wzA);
  prep_bn<<<1, 256, 0, stream>>>(gamma_x, beta_x, mean_x, var_x, bnx);
  prep_bn<<<1, 256, 0, stream>>>(gamma_z, beta_z, mean_z, var_z, bnz);

  conv_gemm<32, 32, 30, 30, 32><<<dim3(450, 2), 256, 0, stream>>>(xb, wxA, bnx, xfh);
  conv_gemm<16, 16, 14, 14, 16><<<dim3(98, 2), 256, 0, stream>>>(zb, wzA, bnz, zfh);

  xcorr_dw3<<<(16384 + 2) / 3, 256, 0, stream>>>(zfh, xfh, out);
}

// Round 4
// 331.173 us; speedup vs baseline: 3.0710x; 1.0804x over previous
//
#include <hip/hip_runtime.h>
#include <cstdint>
#include <cstddef>

typedef _Float16 f16;
typedef _Float16 half4 __attribute__((ext_vector_type(4)));
typedef _Float16 half8 __attribute__((ext_vector_type(8)));
typedef float f32x4 __attribute__((ext_vector_type(4)));

#define BN_EPS 1e-5f

// ---------------- workspace layout (bytes) ----------------
static constexpr size_t OFF_XB  = 0;          // f16 [64][32][32][256] NHWC      33,554,432
static constexpr size_t OFF_ZB  = 33554432;   // f16 [64][16][16][256] NHWC       8,388,608
static constexpr size_t OFF_WX  = 41943040;   // f16 [9][256][256]                1,179,648
static constexpr size_t OFF_WZ  = 43122688;   // f16 [9][256][256]                1,179,648
static constexpr size_t OFF_BNX = 44302336;   // f32 scale[256], bias[256]            2,048
static constexpr size_t OFF_BNZ = 44304384;   //                                      2,048
static constexpr size_t OFF_XFH = 44306432;   // f16 [16384][30][32]             31,457,280
static constexpr size_t OFF_ZFH = 75763712;   // f16 [16384][14][16]              7,340,032

// ---------------- fused prep: transposes + weight repack + BN fold ----------------
// blocks 0..8191: x NCHW->NHWC f16 ; 8192..12287: z ; 12288..16895: weights ; 16896: BN
__global__ __launch_bounds__(256) void prep_all(
    const float* __restrict__ x, const float* __restrict__ z,
    const float* __restrict__ w_x, const float* __restrict__ w_z,
    const float* __restrict__ gx, const float* __restrict__ bx,
    const float* __restrict__ mx, const float* __restrict__ vx,
    const float* __restrict__ gz, const float* __restrict__ bz,
    const float* __restrict__ mz, const float* __restrict__ vz,
    f16* __restrict__ xb, f16* __restrict__ zb,
    f16* __restrict__ wxA, f16* __restrict__ wzA,
    float* __restrict__ bnx, float* __restrict__ bnz) {
  __shared__ float tile[64][33];
  const int bid = blockIdx.x;
  const int tid = threadIdx.x;
  if (bid < 12288) {
    const float* src; f16* dst; int lw, r;
    if (bid < 8192) { src = x; dst = xb; lw = 5; r = bid; }
    else            { src = z; dst = zb; lw = 4; r = bid - 8192; }
    const int W = 1 << lw;           // H == W
    const int c0 = (r & 3) << 6;
    const int h = (r >> 2) & (W - 1);
    const int b = (r >> 2) >> lw;
    const float* sp = src + (size_t)(((b << 8) + c0) << lw << lw) + ((size_t)h << lw);
    const int n = W << 6;  // 64*W
    for (int i = tid; i < n; i += 256) {
      int cl = i >> lw, w = i & (W - 1);
      tile[cl][w] = sp[(size_t)cl << lw << lw | w];
    }
    __syncthreads();
    f16* dp = dst + ((size_t)((b << lw) + h) << lw << 8) + c0;
    for (int i = tid; i < n; i += 256) {
      int w = i >> 6, cl = i & 63;
      dp[(w << 8) + cl] = (f16)tile[cl][w];
    }
  } else if (bid < 16896) {
    int r = bid - 12288;
    const float* src = (r < 2304) ? w_x : w_z;
    f16* dst = (r < 2304) ? wxA : wzA;
    int rr = (r < 2304) ? r : r - 2304;
    int idx = rr * 256 + tid;
    int cin = idx & 255, cout = (idx >> 8) & 255, khw = idx >> 16;
    dst[idx] = (f16)src[(cout * 256 + cin) * 9 + khw];
  } else {
    int c = tid;
    float iv = gx[c] / sqrtf(vx[c] + BN_EPS);
    bnx[c] = iv;
    bnx[256 + c] = bx[c] - mx[c] * iv;
    float iz = gz[c] / sqrtf(vz[c] + BN_EPS);
    bnz[c] = iz;
    bnz[256 + c] = bz[c] - mz[c] * iz;
  }
}

// ---------------- unified implicit-im2col conv3x3 + BN (MFMA f16), BK=64 ----------------
__device__ __forceinline__ void gl_lds16(const f16* g, f16* l) {
  __builtin_amdgcn_global_load_lds((__attribute__((address_space(1))) void*)g,
                                   (__attribute__((address_space(3))) void*)l, 16, 0, 0);
}

// blocks 0..899: conv_x (450 n-tiles x 2 m, interleaved m adjacent for L2 B-sharing)
// blocks 900..1095: conv_z (98 n-tiles x 2 m)
__global__ __launch_bounds__(256, 4) void conv_gemm_u(
    const f16* __restrict__ xb, const f16* __restrict__ zb,
    const f16* __restrict__ wx, const f16* __restrict__ wz,
    const float* __restrict__ bnx, const float* __restrict__ bnz,
    f16* __restrict__ xfh, f16* __restrict__ zfh) {
  __shared__ f16 As[128 * 64];  // [cout_local][k64]  rows of 128B, XOR-swizzled 16B chunks
  __shared__ f16 Bs[128 * 64];  // [n_local][k64]
  const int bid = blockIdx.x;
  const f16* inp; const f16* wA; const float* bn; f16* out;
  int nblk, mblk, HIN, WIN, WOUT, NPIX, WPAD, OPLANE;
  if (bid < 900) {
    inp = xb; wA = wx; bn = bnx; out = xfh;
    nblk = bid >> 1; mblk = bid & 1;
    HIN = 32; WIN = 32; WOUT = 30; NPIX = 900; WPAD = 32; OPLANE = 960;
  } else {
    int r = bid - 900;
    inp = zb; wA = wz; bn = bnz; out = zfh;
    nblk = r >> 1; mblk = r & 1;
    HIN = 16; WIN = 16; WOUT = 14; NPIX = 196; WPAD = 16; OPLANE = 224;
  }
  const int tid = threadIdx.x;
  const int wid = tid >> 6, lane = tid & 63;
  const int wm = (wid >> 1) << 6, wn = (wid & 1) << 6;
  const int q = lane >> 4, lm = lane & 15;
  const int sr = lane >> 3, sc = lane & 7;   // staging: 8 rows x 8 chunks of 16B
  const int swz = (sc ^ sr) << 3;            // LDS slot sc holds global chunk sc^(row&7)
  const int mbase = mblk << 7;

  // staging base addresses (half-element offsets), 4 loads per matrix per wave
  int arow[4], brow[4];
#pragma unroll
  for (int l = 0; l < 4; ++l) {
    int rr = (wid << 5) + (l << 3) + sr;
    arow[l] = ((mbase + rr) << 8) + swz;
    int n = (nblk << 7) + rr;
    int b = n / NPIX, rem = n - b * NPIX;
    int oh = rem / WOUT, ow = rem - oh * WOUT;
    brow[l] = (((b * HIN + oh) * WIN + ow) << 8) + swz;
  }

  f32x4 acc[4][4] = {};
  const int cA0 = (q ^ (lm & 7)) << 3;  // h=0 fragment chunk offset (halves); h=1: ^32

  for (int kt = 0; kt < 36; ++kt) {
    const int khw = kt >> 2;
    const int cin0 = (kt & 3) << 6;
    const int kh = khw / 3, kw = khw - kh * 3;
    const int wofs = (khw << 16) + cin0;
    const int iofs = ((kh * WIN + kw) << 8) + cin0;
#pragma unroll
    for (int l = 0; l < 4; ++l) {
      const int ldso = ((wid << 5) + (l << 3)) << 6;
      gl_lds16(wA + wofs + arow[l], As + ldso);
      gl_lds16(inp + iofs + brow[l], Bs + ldso);
    }
    __syncthreads();
#pragma unroll
    for (int h = 0; h < 2; ++h) {
      const int co = cA0 ^ (h << 5);
      half8 af[4], bf[4];
#pragma unroll
      for (int f = 0; f < 4; ++f) {
        af[f] = *(const half8*)&As[((wm + (f << 4) + lm) << 6) + co];
        bf[f] = *(const half8*)&Bs[((wn + (f << 4) + lm) << 6) + co];
      }
#pragma unroll
      for (int fm = 0; fm < 4; ++fm)
#pragma unroll
        for (int fn = 0; fn < 4; ++fn)
          acc[fm][fn] =
              __builtin_amdgcn_mfma_f32_16x16x32_f16(af[fm], bf[fn], acc[fm][fn], 0, 0, 0);
    }
    __syncthreads();
  }

  // epilogue: BN + f16 padded store. C/D: row m = q*4+reg, col n = lm.
#pragma unroll
  for (int fn = 0; fn < 4; ++fn) {
    int n_g = (nblk << 7) + wn + (fn << 4) + lm;
    int b = n_g / NPIX, rem = n_g - b * NPIX;
    int oh = rem / WOUT, ow = rem - oh * WOUT;
    f16* op = out + (size_t)(b << 8) * OPLANE + oh * WPAD + ow;
#pragma unroll
    for (int fm = 0; fm < 4; ++fm) {
      int m0 = mbase + wm + (fm << 4) + (q << 2);
#pragma unroll
      for (int rg = 0; rg < 4; ++rg) {
        int m = m0 + rg;
        op[(size_t)m * OPLANE] = (f16)(acc[fm][fn][rg] * bn[m] + bn[256 + m]);
      }
    }
  }
}

// ---------------- depthwise xcorr v3 (unchanged) ----------------
static constexpr int XST = 40;
static constexpr int XCH = 30 * XST;
static constexpr int ZCH = 14 * 16;

__global__ __launch_bounds__(256) void xcorr_dw3(const f16* __restrict__ zfh,
                                                 const f16* __restrict__ xfh,
                                                 float* __restrict__ out) {
  __shared__ f16 xs[3 * XCH];
  __shared__ f16 zs[3 * ZCH];
  const int t = threadIdx.x;
  const int ch0 = blockIdx.x * 3;

  for (int i = t; i < 360; i += 256) {
    int ch = i / 120, rem = i - ch * 120;
    int row = rem >> 2, col = (rem & 3) << 3;
    if (ch0 + ch < 16384)
      *(half8*)(xs + ch * XCH + row * XST + col) =
          *(const half8*)(xfh + (size_t)(ch0 + ch) * 960 + row * 32 + col);
  }
  for (int i = t; i < 84; i += 256) {
    int ch = i / 28, rem = i - ch * 28;
    if (ch0 + ch < 16384)
      *(half8*)(zs + ch * ZCH + rem * 8) =
          *(const half8*)(zfh + (size_t)(ch0 + ch) * 224 + rem * 8);
  }
  __syncthreads();

  int lc = t / 85;
  int r = t - lc * 85;
  const bool ok = (lc < 3) && (ch0 + lc < 16384);
  if (lc > 2) lc = 2;
  const int oy = r / 5, oxq = r - oy * 5, ox0 = oxq * 4;
  const f16* xbp = xs + lc * XCH;
  const f16* zbp = zs + lc * ZCH;

  float acc[4] = {0.f, 0.f, 0.f, 0.f};

#pragma unroll 2
  for (int u = 0; u < 14; ++u) {
    float xr[20];
#pragma unroll
    for (int k = 0; k < 5; ++k) {
      half4 h = *(const half4*)(xbp + (oy + u) * XST + ox0 + k * 4);
#pragma unroll
      for (int e = 0; e < 4; ++e) xr[k * 4 + e] = (float)h[e];
    }
    float zc[14];
    {
      half8 z0 = *(const half8*)(zbp + u * 16);
      half8 z1 = *(const half8*)(zbp + u * 16 + 8);
#pragma unroll
      for (int e = 0; e < 8; ++e) zc[e] = (float)z0[e];
#pragma unroll
      for (int e = 0; e < 6; ++e) zc[8 + e] = (float)z1[e];
    }
#pragma unroll
    for (int v = 0; v < 14; ++v)
#pragma unroll
      for (int j = 0; j < 4; ++j) acc[j] = fmaf(zc[v], xr[v + j], acc[j]);
  }

  if (ok) {
    float* op = out + (size_t)(ch0 + lc) * 289 + oy * 17;
#pragma unroll
    for (int j = 0; j < 4; ++j) {
      int ox = ox0 + j;
      if (ox < 17) op[ox] = acc[j];
    }
  }
}

extern "C" void kernel_launch(void* const* d_in, const int* in_sizes, int n_in,
                              void* d_out, int out_size, void* d_ws, size_t ws_size,
                              hipStream_t stream) {
  const float* z = (const float*)d_in[0];
  const float* x = (const float*)d_in[1];
  const float* w_z = (const float*)d_in[2];
  const float* w_x = (const float*)d_in[3];
  const float* gamma_z = (const float*)d_in[4];
  const float* beta_z = (const float*)d_in[5];
  const float* mean_z = (const float*)d_in[6];
  const float* var_z = (const float*)d_in[7];
  const float* gamma_x = (const float*)d_in[8];
  const float* beta_x = (const float*)d_in[9];
  const float* mean_x = (const float*)d_in[10];
  const float* var_x = (const float*)d_in[11];

  char* ws = (char*)d_ws;
  f16* xb = (f16*)(ws + OFF_XB);
  f16* zb = (f16*)(ws + OFF_ZB);
  f16* wxA = (f16*)(ws + OFF_WX);
  f16* wzA = (f16*)(ws + OFF_WZ);
  float* bnx = (float*)(ws + OFF_BNX);
  float* bnz = (float*)(ws + OFF_BNZ);
  f16* xfh = (f16*)(ws + OFF_XFH);
  f16* zfh = (f16*)(ws + OFF_ZFH);
  float* out = (float*)d_out;

  prep_all<<<16897, 256, 0, stream>>>(x, z, w_x, w_z,
                                      gamma_x, beta_x, mean_x, var_x,
                                      gamma_z, beta_z, mean_z, var_z,
                                      xb, zb, wxA, wzA, bnx, bnz);

  conv_gemm_u<<<1096, 256, 0, stream>>>(xb, zb, wxA, wzA, bnx, bnz, xfh, zfh);

  xcorr_dw3<<<(16384 + 2) / 3, 256, 0, stream>>>(zfh, xfh, out);
}